// Round 1
// baseline (42.922 us; speedup 1.0000x reference)
//
#include <hip/hip_runtime.h>

#define ALPHA 0.002
#define NITER 100

// Kernel 1: compute P = M^100 and Q = ALPHA * sum_{k=0}^{99} M^k, where
// M = I - ALPHA*A. One block of 64 threads; thread tid owns element
// (i,j) = (tid>>3, tid&7). fp64 accumulation, fp32 output into d_ws:
//   d_ws[0..63]   = P (row-major)
//   d_ws[64..127] = Q (row-major)
__global__ __launch_bounds__(64) void build_PQ(const float* __restrict__ A,
                                               float* __restrict__ PQ) {
    const int tid = threadIdx.x;
    const int i = tid >> 3, j = tid & 7;
    __shared__ double Ms[64];
    __shared__ double Ps[64];

    const double m = ((i == j) ? 1.0 : 0.0) - (double)ALPHA * (double)A[tid];
    Ms[tid] = m;
    __syncthreads();

    // Each thread preloads column j of M into registers (read once).
    double Mcol[8];
#pragma unroll
    for (int t = 0; t < 8; ++t) Mcol[t] = Ms[t * 8 + j];

    double P = (i == j) ? 1.0 : 0.0;  // M^0 = I
    double S = 0.0;                   // sum_{t<k} M^t

    for (int k = 0; k < NITER; ++k) {
        S += P;
        __syncthreads();   // previous iteration's reads of Ps are done
        Ps[tid] = P;
        __syncthreads();   // Ps fully written
        double acc = 0.0;
#pragma unroll
        for (int t = 0; t < 8; ++t) acc += Ps[i * 8 + t] * Mcol[t];
        P = acc;           // P <- P * M
    }

    PQ[tid]      = (float)P;
    PQ[64 + tid] = (float)((double)ALPHA * S);
}

// Kernel 2: out[row] = x[row]*P + y[row]*Q. One row (8 floats) per thread,
// float4 loads/stores, P/Q broadcast from LDS.
__global__ __launch_bounds__(256) void apply_PQ(const float* __restrict__ x,
                                                const float* __restrict__ y,
                                                const float* __restrict__ PQ,
                                                float* __restrict__ out,
                                                int nrows) {
    __shared__ float sP[64];
    __shared__ float sQ[64];
    if (threadIdx.x < 64) {
        sP[threadIdx.x] = PQ[threadIdx.x];
        sQ[threadIdx.x] = PQ[64 + threadIdx.x];
    }
    __syncthreads();

    const int row = blockIdx.x * blockDim.x + threadIdx.x;
    if (row >= nrows) return;

    const float4* xr = (const float4*)(x + (size_t)row * 8);
    const float4* yr = (const float4*)(y + (size_t)row * 8);
    const float4 x0 = xr[0], x1 = xr[1];
    const float4 y0 = yr[0], y1 = yr[1];
    const float xv[8] = {x0.x, x0.y, x0.z, x0.w, x1.x, x1.y, x1.z, x1.w};
    const float yv[8] = {y0.x, y0.y, y0.z, y0.w, y1.x, y1.y, y1.z, y1.w};

    float ov[8];
#pragma unroll
    for (int jj = 0; jj < 8; ++jj) {
        float acc = 0.0f;
#pragma unroll
        for (int t = 0; t < 8; ++t) acc = fmaf(xv[t], sP[t * 8 + jj], acc);
#pragma unroll
        for (int t = 0; t < 8; ++t) acc = fmaf(yv[t], sQ[t * 8 + jj], acc);
        ov[jj] = acc;
    }

    float4* orow = (float4*)(out + (size_t)row * 8);
    orow[0] = make_float4(ov[0], ov[1], ov[2], ov[3]);
    orow[1] = make_float4(ov[4], ov[5], ov[6], ov[7]);
}

extern "C" void kernel_launch(void* const* d_in, const int* in_sizes, int n_in,
                              void* d_out, int out_size, void* d_ws, size_t ws_size,
                              hipStream_t stream) {
    const float* x = (const float*)d_in[0];
    const float* y = (const float*)d_in[1];
    const float* A = (const float*)d_in[2];
    float* out = (float*)d_out;
    float* PQ  = (float*)d_ws;  // 128 floats

    const int nrows = in_sizes[0] / 8;  // 2,000,000

    build_PQ<<<1, 64, 0, stream>>>(A, PQ);

    const int block = 256;
    const int grid = (nrows + block - 1) / block;
    apply_PQ<<<grid, block, 0, stream>>>(x, y, PQ, out, nrows);
}